// Round 1
// baseline (509.485 us; speedup 1.0000x reference)
//
#include <hip/hip_runtime.h>
#include <hip/hip_bf16.h>

// Bahdanau attention, MI355X. B=64 S=1024 E=1024 D=512.
// GEMM view: M = B*S = 65536, K = E = 1024, N = D = 512.

typedef __attribute__((ext_vector_type(4))) float f32x4;
typedef __attribute__((ext_vector_type(8))) short short8;
typedef __attribute__((ext_vector_type(8))) __bf16 bf16x8;

__device__ __forceinline__ void gload_lds16(const void* g, void* l) {
  __builtin_amdgcn_global_load_lds(
      (const __attribute__((address_space(1))) unsigned int*)g,
      (__attribute__((address_space(3))) unsigned int*)l,
      16, 0, 0);
}

__device__ __forceinline__ unsigned short f2bf_rne(float f) {
  union { float f; unsigned int u; } v; v.f = f;
  unsigned int r = v.u + 0x7FFFu + ((v.u >> 16) & 1u);
  return (unsigned short)(r >> 16);
}

__device__ __forceinline__ float fast_tanh(float x) {
  float e = __expf(2.0f * x);                      // inf-safe: e=inf -> 1, e=0 -> -1
  return 1.0f - 2.0f * __builtin_amdgcn_rcpf(e + 1.0f);
}

// ---- h_proj: hb[b][d] = sum_k hidden[b][k] * attn_W[k][d]   (bias folded later)
__global__ void hproj_kernel(const float* __restrict__ hidden,
                             const float* __restrict__ attn_W,
                             float* __restrict__ hb /* zeroed */) {
  int b = blockIdx.x >> 2, kc = blockIdx.x & 3;
  int tid = threadIdx.x;
  __shared__ float hrow[128];
  if (tid < 128) hrow[tid] = hidden[b * 512 + kc * 128 + tid];
  __syncthreads();
  const float* Wp = attn_W + (size_t)(kc * 128) * 512;
  float a0 = 0.f, a1 = 0.f;
#pragma unroll 4
  for (int k = 0; k < 128; ++k) {
    float h = hrow[k];
    a0 = fmaf(h, Wp[(size_t)k * 512 + tid], a0);
    a1 = fmaf(h, Wp[(size_t)k * 512 + tid + 256], a1);
  }
  atomicAdd(&hb[b * 512 + tid], a0);
  atomicAdd(&hb[b * 512 + tid + 256], a1);
}

// ---- W_e transpose+convert: weT[d][e] = bf16(attn_W[512+e][d]),  [512][1024] bf16
__global__ void wet_kernel(const float* __restrict__ attn_W,
                           unsigned short* __restrict__ weT) {
  __shared__ float tile[64][65];
  int bx = blockIdx.x;
  int kt = bx & 15;          // e-tile (16)
  int nt = bx >> 4;          // d-tile (8)
  int tid = threadIdx.x;
  int j = tid & 63, i = tid >> 6;
  const float* src = attn_W + (size_t)(512 + kt * 64) * 512 + nt * 64;
#pragma unroll
  for (int p = 0; p < 16; ++p) {
    int r = p * 4 + i;
    tile[r][j] = src[(size_t)r * 512 + j];
  }
  __syncthreads();
  unsigned short* dst = weT + (size_t)(nt * 64) * 1024 + kt * 64;
#pragma unroll
  for (int p = 0; p < 16; ++p) {
    int c = p * 4 + i;
    dst[(size_t)c * 1024 + j] = f2bf_rne(tile[j][c]);
  }
}

// ---- fused e_proj GEMM + tanh + dot(v) -> scores, 128x128 tile, BK=64, 4 waves 2x2
__global__ __launch_bounds__(256) void fused_score_gemm(
    const float* __restrict__ enc,            // [65536][1024] fp32 (A)
    const unsigned short* __restrict__ weT,   // [512][1024] bf16  (B rows = N)
    const float* __restrict__ hb,             // [64][512]
    const float* __restrict__ attn_b,         // [512]
    const float* __restrict__ vW,             // [512]
    float* __restrict__ scores)               // [65536], zeroed
{
  __shared__ float At[128 * 64];              // 32 KB, source-swizzled 16B chunks
  __shared__ unsigned short Bt[128 * 64];     // 16 KB, source-swizzled 16B chunks

  int bx = blockIdx.x;
  int wg = ((bx & 7) << 8) | (bx >> 3);       // XCD swizzle (nwg=2048, %8==0)
  int m0 = (wg >> 2) << 7;                    // n fastest -> A-panel L2 reuse
  int n0 = (wg & 3) << 7;

  int tid = threadIdx.x;
  int w = tid >> 6, l = tid & 63;
  int g = l >> 4, l15 = l & 15;
  int wm = (w >> 1) << 6, wn = (w & 1) << 6;

  // staging source element offsets (tile-constant)
  int aSrc[8];
#pragma unroll
  for (int i = 0; i < 8; ++i) {
    int c = ((i * 4 + w) << 6) | l;           // 16B chunk id, 2048 total
    int row = c >> 4, s16 = c & 15;           // 16 chunks per 256B row
    aSrc[i] = row * 1024 + ((s16 ^ (row & 7)) << 2);   // floats
  }
  int bSrc[4];
#pragma unroll
  for (int i = 0; i < 4; ++i) {
    int c = ((i * 4 + w) << 6) | l;           // 1024 chunks
    int row = c >> 3, s16 = c & 7;            // 8 chunks per 128B row
    bSrc[i] = row * 1024 + ((s16 ^ (row & 7)) << 3);   // bf16 elems
  }

  const float* Ab = enc + (size_t)m0 * 1024;
  const unsigned short* Bb = weT + (size_t)n0 * 1024;

  f32x4 zero = {0.f, 0.f, 0.f, 0.f};
  f32x4 acc[4][4];
#pragma unroll
  for (int i = 0; i < 4; ++i)
#pragma unroll
    for (int j = 0; j < 4; ++j) acc[i][j] = zero;

  // LDS read byte offsets (constant across K loop)
  int aRd[4][2][2], bRd[4][2];
#pragma unroll
  for (int mt = 0; mt < 4; ++mt) {
    int row = wm + mt * 16 + l15;
#pragma unroll
    for (int kk = 0; kk < 2; ++kk) {
      int s = kk * 8 + g * 2;
      aRd[mt][kk][0] = row * 256 + ((s ^ (row & 7)) << 4);
      aRd[mt][kk][1] = row * 256 + (((s + 1) ^ (row & 7)) << 4);
    }
  }
#pragma unroll
  for (int nt = 0; nt < 4; ++nt) {
    int row = wn + nt * 16 + l15;
#pragma unroll
    for (int kk = 0; kk < 2; ++kk) {
      int s = kk * 4 + g;
      bRd[nt][kk] = row * 128 + ((s ^ (row & 7)) << 4);
    }
  }

  const char* Atc = (const char*)At;
  const char* Btc = (const char*)Bt;

  for (int kt = 0; kt < 16; ++kt) {
    int k0 = kt << 6;
#pragma unroll
    for (int i = 0; i < 8; ++i)
      gload_lds16(Ab + aSrc[i] + k0, (char*)At + ((i * 4 + w) << 10));
#pragma unroll
    for (int i = 0; i < 4; ++i)
      gload_lds16(Bb + bSrc[i] + k0, (char*)Bt + ((i * 4 + w) << 10));
    __syncthreads();

#pragma unroll
    for (int kk = 0; kk < 2; ++kk) {
      short8 af[4], bfr[4];
#pragma unroll
      for (int mt = 0; mt < 4; ++mt) {
        f32x4 lo = *(const f32x4*)(Atc + aRd[mt][kk][0]);
        f32x4 hi = *(const f32x4*)(Atc + aRd[mt][kk][1]);
        bf16x8 a;
        a[0] = (__bf16)lo[0]; a[1] = (__bf16)lo[1];
        a[2] = (__bf16)lo[2]; a[3] = (__bf16)lo[3];
        a[4] = (__bf16)hi[0]; a[5] = (__bf16)hi[1];
        a[6] = (__bf16)hi[2]; a[7] = (__bf16)hi[3];
        af[mt] = __builtin_bit_cast(short8, a);
      }
#pragma unroll
      for (int nt = 0; nt < 4; ++nt)
        bfr[nt] = *(const short8*)(Btc + bRd[nt][kk]);
#pragma unroll
      for (int mt = 0; mt < 4; ++mt)
#pragma unroll
        for (int nt = 0; nt < 4; ++nt)
          acc[mt][nt] = __builtin_amdgcn_mfma_f32_16x16x32_bf16(
              af[mt], bfr[nt], acc[mt][nt], 0, 0, 0);
    }
    __syncthreads();
  }

  // epilogue: scores[m] += sum_d tanh(acc + h_proj + bias) * v
  int b = m0 >> 10;
  float hbv[4], vwv[4];
#pragma unroll
  for (int nt = 0; nt < 4; ++nt) {
    int d = n0 + wn + nt * 16 + l15;
    hbv[nt] = hb[(b << 9) + d] + attn_b[d];
    vwv[nt] = vW[d];
  }
#pragma unroll
  for (int mt = 0; mt < 4; ++mt) {
#pragma unroll
    for (int j = 0; j < 4; ++j) {
      float p = 0.f;
#pragma unroll
      for (int nt = 0; nt < 4; ++nt)
        p = fmaf(fast_tanh(acc[mt][nt][j] + hbv[nt]), vwv[nt], p);
      p += __shfl_xor(p, 1);
      p += __shfl_xor(p, 2);
      p += __shfl_xor(p, 4);
      p += __shfl_xor(p, 8);
      if (l15 == 0)
        atomicAdd(&scores[m0 + wm + mt * 16 + (g << 2) + j], p);
    }
  }
}

// ---- masked softmax over S per batch
__global__ void softmax_kernel(const float* __restrict__ scores,
                               const int* __restrict__ mask,
                               float* __restrict__ attn_out) {
  int b = blockIdx.x, tid = threadIdx.x;
  __shared__ float red[256];
  const float NEG = -3.402823466e38f;
  float v[4];
  float mx = NEG;
#pragma unroll
  for (int i = 0; i < 4; ++i) {
    int s = (i << 8) + tid;
    float sc = scores[(b << 10) + s];
    v[i] = (mask[(b << 10) + s] == 0) ? NEG : sc;
    mx = fmaxf(mx, v[i]);
  }
  red[tid] = mx; __syncthreads();
  for (int off = 128; off > 0; off >>= 1) {
    if (tid < off) red[tid] = fmaxf(red[tid], red[tid + off]);
    __syncthreads();
  }
  mx = red[0]; __syncthreads();
  float sum = 0.f;
#pragma unroll
  for (int i = 0; i < 4; ++i) { v[i] = __expf(v[i] - mx); sum += v[i]; }
  red[tid] = sum; __syncthreads();
  for (int off = 128; off > 0; off >>= 1) {
    if (tid < off) red[tid] += red[tid + off];
    __syncthreads();
  }
  float inv = 1.f / red[0];
#pragma unroll
  for (int i = 0; i < 4; ++i)
    attn_out[(b << 10) + (i << 8) + tid] = v[i] * inv;
}

// ---- context[b][e] = sum_s w[b][s] * enc[b][s][e]
__global__ void context_kernel(const float* __restrict__ wts,
                               const float* __restrict__ enc,
                               float* __restrict__ ctx /* zeroed */) {
  int bx = blockIdx.x;
  int b = bx >> 4, ech = (bx >> 2) & 3, sch = bx & 3;
  int e = (ech << 8) + threadIdx.x;
  const float* encp = enc + (size_t)((b << 10) + (sch << 8)) * 1024 + e;
  const float* wp = wts + (b << 10) + (sch << 8);
  float a0 = 0.f, a1 = 0.f, a2 = 0.f, a3 = 0.f;
  for (int s = 0; s < 256; s += 4) {
    a0 = fmaf(wp[s + 0], encp[(size_t)(s + 0) << 10], a0);
    a1 = fmaf(wp[s + 1], encp[(size_t)(s + 1) << 10], a1);
    a2 = fmaf(wp[s + 2], encp[(size_t)(s + 2) << 10], a2);
    a3 = fmaf(wp[s + 3], encp[(size_t)(s + 3) << 10], a3);
  }
  atomicAdd(&ctx[(b << 10) + e], a0 + a1 + a2 + a3);
}

extern "C" void kernel_launch(void* const* d_in, const int* in_sizes, int n_in,
                              void* d_out, int out_size, void* d_ws, size_t ws_size,
                              hipStream_t stream) {
  const float* hidden = (const float*)d_in[0];
  const float* enc    = (const float*)d_in[1];
  const int*   mask   = (const int*)d_in[2];
  const float* attn_W = (const float*)d_in[3];
  const float* attn_b = (const float*)d_in[4];
  const float* vW     = (const float*)d_in[5];
  float* out = (float*)d_out;   // [0,65536): context ; [65536,131072): attn_weights

  float* scores = (float*)d_ws;                        // 65536 f32
  float* hb     = scores + 65536;                      // 32768 f32
  unsigned short* weT = (unsigned short*)(hb + 32768); // 524288 bf16 (1 MB)

  hipMemsetAsync(d_ws, 0, (65536 + 32768) * sizeof(float), stream); // scores + hb
  hipMemsetAsync(d_out, 0, 65536 * sizeof(float), stream);          // context region

  hproj_kernel<<<256, 256, 0, stream>>>(hidden, attn_W, hb);
  wet_kernel<<<128, 256, 0, stream>>>(attn_W, weT);
  fused_score_gemm<<<2048, 256, 0, stream>>>(enc, weT, hb, attn_b, vW, scores);
  softmax_kernel<<<64, 256, 0, stream>>>(scores, mask, out + 65536);
  context_kernel<<<1024, 256, 0, stream>>>(out + 65536, enc, out);
}

// Round 2
// 485.318 us; speedup vs baseline: 1.0498x; 1.0498x over previous
//
#include <hip/hip_runtime.h>
#include <hip/hip_bf16.h>

// Bahdanau attention, MI355X. B=64 S=1024 E=1024 D=512.
// GEMM view: M = B*S = 65536, K = E = 1024, N = D = 512.

typedef __attribute__((ext_vector_type(4))) float f32x4;
typedef __attribute__((ext_vector_type(8))) short short8;
typedef __attribute__((ext_vector_type(8))) __bf16 bf16x8;

__device__ __forceinline__ void gload_lds16(const void* g, void* l) {
  __builtin_amdgcn_global_load_lds(
      (const __attribute__((address_space(1))) unsigned int*)g,
      (__attribute__((address_space(3))) unsigned int*)l,
      16, 0, 0);
}

__device__ __forceinline__ unsigned short f2bf_rne(float f) {
  union { float f; unsigned int u; } v; v.f = f;
  unsigned int r = v.u + 0x7FFFu + ((v.u >> 16) & 1u);
  return (unsigned short)(r >> 16);
}

__device__ __forceinline__ float fast_tanh(float x) {
  float e = __expf(2.0f * x);                      // inf-safe: e=inf -> 1, e=0 -> -1
  return 1.0f - 2.0f * __builtin_amdgcn_rcpf(e + 1.0f);
}

// ---- h_proj: hb[b][d] = sum_k hidden[b][k] * attn_W[k][d]
__global__ void hproj_kernel(const float* __restrict__ hidden,
                             const float* __restrict__ attn_W,
                             float* __restrict__ hb /* zeroed */) {
  int b = blockIdx.x >> 2, kc = blockIdx.x & 3;
  int tid = threadIdx.x;
  __shared__ float hrow[128];
  if (tid < 128) hrow[tid] = hidden[b * 512 + kc * 128 + tid];
  __syncthreads();
  const float* Wp = attn_W + (size_t)(kc * 128) * 512;
  float a0 = 0.f, a1 = 0.f;
#pragma unroll 4
  for (int k = 0; k < 128; ++k) {
    float h = hrow[k];
    a0 = fmaf(h, Wp[(size_t)k * 512 + tid], a0);
    a1 = fmaf(h, Wp[(size_t)k * 512 + tid + 256], a1);
  }
  atomicAdd(&hb[b * 512 + tid], a0);
  atomicAdd(&hb[b * 512 + tid + 256], a1);
}

// ---- W_e transpose+convert: weT[d][e] = bf16(attn_W[512+e][d]),  [512][1024] bf16
__global__ void wet_kernel(const float* __restrict__ attn_W,
                           unsigned short* __restrict__ weT) {
  __shared__ float tile[64][65];
  int bx = blockIdx.x;
  int kt = bx & 15;          // e-tile (16)
  int nt = bx >> 4;          // d-tile (8)
  int tid = threadIdx.x;
  int j = tid & 63, i = tid >> 6;
  const float* src = attn_W + (size_t)(512 + kt * 64) * 512 + nt * 64;
#pragma unroll
  for (int p = 0; p < 16; ++p) {
    int r = p * 4 + i;
    tile[r][j] = src[(size_t)r * 512 + j];
  }
  __syncthreads();
  unsigned short* dst = weT + (size_t)(nt * 64) * 1024 + kt * 64;
#pragma unroll
  for (int p = 0; p < 16; ++p) {
    int c = p * 4 + i;
    dst[(size_t)c * 1024 + j] = f2bf_rne(tile[j][c]);
  }
}

// ---- fused e_proj GEMM + tanh + dot(v) -> scores
// 128x128 tile, BK=64, 4 waves 2x2. A reg-staged fp32->bf16 (16 KB LDS),
// B via global_load_lds (16 KB LDS). Total LDS 32 KB.
__global__ __launch_bounds__(256, 4) void fused_score_gemm(
    const float* __restrict__ enc,            // [65536][1024] fp32 (A)
    const unsigned short* __restrict__ weT,   // [512][1024] bf16  (B rows = N)
    const float* __restrict__ hb,             // [64][512]
    const float* __restrict__ attn_b,         // [512]
    const float* __restrict__ vW,             // [512]
    float* __restrict__ scores)               // [65536], zeroed
{
  __shared__ unsigned short At[128 * 64];     // 16 KB, XOR-swizzled 16B slots
  __shared__ unsigned short Bt[128 * 64];     // 16 KB, XOR-swizzled 16B slots

  int bx = blockIdx.x;
  int wg = ((bx & 7) << 8) | (bx >> 3);       // XCD swizzle (nwg=2048, %8==0)
  int m0 = (wg >> 2) << 7;                    // n fastest -> A-panel L2 reuse
  int n0 = (wg & 3) << 7;

  int tid = threadIdx.x;
  int w = tid >> 6, l = tid & 63;
  int g = l >> 4, l15 = l & 15;
  int wm = (w >> 1) << 6, wn = (w & 1) << 6;

  // A staging map (per thread, 4 chunks: c = i*256+tid). row/slot constants:
  //   row = i*32 + (tid>>3), ps = tid&7, global slot sg = ps ^ (row&7).
  //   sg and row&7 are i-invariant -> single base offset + i*32768.
  int arow = tid >> 3;                        // row for i=0
  int aps = tid & 7;
  int asg = aps ^ (arow & 7);
  int aoff0 = arow * 1024 + asg * 8;          // float offset (excl. kt, panel)
  // LDS write byte offset: chunk c*16 = i*4096 + tid*16 (linear -> conflict-free)

  // B staging source (gload_lds, 4 rounds): chunk c = (i*4+w)*64 + l
  int brow = ((w << 6) | l) >> 3;             // row for i=0: (i*4+w)*8 + (l>>3)
  int bps = l & 7;
  int bsg = bps ^ ((l >> 3) & 7);             // row&7 == l>>3 (i-invariant)
  int boff0 = brow * 1024 + bsg * 8;          // bf16 elem offset

  const float* Ab = enc + (size_t)m0 * 1024;
  const unsigned short* Bb = weT + (size_t)n0 * 1024;

  f32x4 zero = {0.f, 0.f, 0.f, 0.f};
  f32x4 acc[4][4];
#pragma unroll
  for (int i = 0; i < 4; ++i)
#pragma unroll
    for (int j = 0; j < 4; ++j) acc[i][j] = zero;

  // LDS read byte offsets (kk=0); kk=1 is XOR 64 (slot-bit2 <-> byte-bit6)
  int aRd[4], bRd[4];
#pragma unroll
  for (int mt = 0; mt < 4; ++mt) {
    int row = wm + mt * 16 + l15;
    aRd[mt] = row * 128 + ((g ^ (row & 7)) << 4);
  }
#pragma unroll
  for (int nt = 0; nt < 4; ++nt) {
    int row = wn + nt * 16 + l15;
    bRd[nt] = row * 128 + ((g ^ (row & 7)) << 4);
  }

  const char* Atc = (const char*)At;
  const char* Btc = (const char*)Bt;

  // prologue: load A(kt=0) into regs
  f32x4 rA[8];
#pragma unroll
  for (int i = 0; i < 4; ++i) {
    rA[2 * i]     = *(const f32x4*)(Ab + aoff0 + i * 32768);
    rA[2 * i + 1] = *(const f32x4*)(Ab + aoff0 + i * 32768 + 4);
  }

  for (int kt = 0; kt < 16; ++kt) {
    int k0n = (kt + (kt < 15)) << 6;          // next-tile k (clamped, redundant last iter)
    __syncthreads();                          // prev readers done
    // stage A: cvt + ds_write_b128 (linear dest)
#pragma unroll
    for (int i = 0; i < 4; ++i) {
      bf16x8 v;
      v[0] = (__bf16)rA[2 * i][0]; v[1] = (__bf16)rA[2 * i][1];
      v[2] = (__bf16)rA[2 * i][2]; v[3] = (__bf16)rA[2 * i][3];
      v[4] = (__bf16)rA[2 * i + 1][0]; v[5] = (__bf16)rA[2 * i + 1][1];
      v[6] = (__bf16)rA[2 * i + 1][2]; v[7] = (__bf16)rA[2 * i + 1][3];
      *(short8*)((char*)At + (i << 12) + (tid << 4)) = __builtin_bit_cast(short8, v);
    }
    // stage B: async global->LDS
#pragma unroll
    for (int i = 0; i < 4; ++i)
      gload_lds16(Bb + boff0 + i * 32768 + (kt << 6),
                  (char*)Bt + ((i * 4 + w) << 10));
    __syncthreads();                          // writes visible (lgkm + vmcnt drain)
    // prefetch next A into regs -- overlaps the compute phase below
#pragma unroll
    for (int i = 0; i < 4; ++i) {
      rA[2 * i]     = *(const f32x4*)(Ab + aoff0 + i * 32768 + k0n);
      rA[2 * i + 1] = *(const f32x4*)(Ab + aoff0 + i * 32768 + k0n + 4);
    }
    // compute
#pragma unroll
    for (int kk = 0; kk < 2; ++kk) {
      int kx = kk << 6;
      short8 af[4], bfm[4];
#pragma unroll
      for (int mt = 0; mt < 4; ++mt)
        af[mt] = *(const short8*)(Atc + (aRd[mt] ^ kx));
#pragma unroll
      for (int nt = 0; nt < 4; ++nt)
        bfm[nt] = *(const short8*)(Btc + (bRd[nt] ^ kx));
#pragma unroll
      for (int mt = 0; mt < 4; ++mt)
#pragma unroll
        for (int nt = 0; nt < 4; ++nt)
          acc[mt][nt] = __builtin_amdgcn_mfma_f32_16x16x32_bf16(
              af[mt], bfm[nt], acc[mt][nt], 0, 0, 0);
    }
  }

  // epilogue: scores[m] += sum_d tanh(acc + h_proj + bias) * v
  int b = m0 >> 10;
  float hbv[4], vwv[4];
#pragma unroll
  for (int nt = 0; nt < 4; ++nt) {
    int d = n0 + wn + nt * 16 + l15;
    hbv[nt] = hb[(b << 9) + d] + attn_b[d];
    vwv[nt] = vW[d];
  }
#pragma unroll
  for (int mt = 0; mt < 4; ++mt) {
#pragma unroll
    for (int j = 0; j < 4; ++j) {
      float p = 0.f;
#pragma unroll
      for (int nt = 0; nt < 4; ++nt)
        p = fmaf(fast_tanh(acc[mt][nt][j] + hbv[nt]), vwv[nt], p);
      p += __shfl_xor(p, 1);
      p += __shfl_xor(p, 2);
      p += __shfl_xor(p, 4);
      p += __shfl_xor(p, 8);
      if (l15 == 0)
        atomicAdd(&scores[m0 + wm + mt * 16 + (g << 2) + j], p);
    }
  }
}

// ---- masked softmax over S per batch
__global__ void softmax_kernel(const float* __restrict__ scores,
                               const int* __restrict__ mask,
                               float* __restrict__ attn_out) {
  int b = blockIdx.x, tid = threadIdx.x;
  __shared__ float red[256];
  const float NEG = -3.402823466e38f;
  float v[4];
  float mx = NEG;
#pragma unroll
  for (int i = 0; i < 4; ++i) {
    int s = (i << 8) + tid;
    float sc = scores[(b << 10) + s];
    v[i] = (mask[(b << 10) + s] == 0) ? NEG : sc;
    mx = fmaxf(mx, v[i]);
  }
  red[tid] = mx; __syncthreads();
  for (int off = 128; off > 0; off >>= 1) {
    if (tid < off) red[tid] = fmaxf(red[tid], red[tid + off]);
    __syncthreads();
  }
  mx = red[0]; __syncthreads();
  float sum = 0.f;
#pragma unroll
  for (int i = 0; i < 4; ++i) { v[i] = __expf(v[i] - mx); sum += v[i]; }
  red[tid] = sum; __syncthreads();
  for (int off = 128; off > 0; off >>= 1) {
    if (tid < off) red[tid] += red[tid + off];
    __syncthreads();
  }
  float inv = 1.f / red[0];
#pragma unroll
  for (int i = 0; i < 4; ++i)
    attn_out[(b << 10) + (i << 8) + tid] = v[i] * inv;
}

// ---- context[b][e] = sum_s w[b][s] * enc[b][s][e]   (float4-vectorized)
__global__ void context_kernel(const float* __restrict__ wts,
                               const float* __restrict__ enc,
                               float* __restrict__ ctx /* zeroed */) {
  int bx = blockIdx.x;                        // 1024 = 64 b x 16 s-chunks
  int b = bx >> 4, sch = bx & 15;
  int tid = threadIdx.x;                      // 256 threads x float4 = 1024 e
  const float* encp = enc + ((size_t)(b << 10) + (sch << 6)) * 1024 + (tid << 2);
  const float* wp = wts + (b << 10) + (sch << 6);
  f32x4 a0 = {0.f, 0.f, 0.f, 0.f}, a1 = a0, a2 = a0, a3 = a0;
  for (int s = 0; s < 64; s += 4) {
    float w0 = wp[s], w1 = wp[s + 1], w2 = wp[s + 2], w3 = wp[s + 3];
    f32x4 v0 = *(const f32x4*)(encp + ((size_t)(s + 0) << 10));
    f32x4 v1 = *(const f32x4*)(encp + ((size_t)(s + 1) << 10));
    f32x4 v2 = *(const f32x4*)(encp + ((size_t)(s + 2) << 10));
    f32x4 v3 = *(const f32x4*)(encp + ((size_t)(s + 3) << 10));
#pragma unroll
    for (int j = 0; j < 4; ++j) {
      a0[j] = fmaf(w0, v0[j], a0[j]);
      a1[j] = fmaf(w1, v1[j], a1[j]);
      a2[j] = fmaf(w2, v2[j], a2[j]);
      a3[j] = fmaf(w3, v3[j], a3[j]);
    }
  }
  float* dst = ctx + (b << 10) + (tid << 2);
#pragma unroll
  for (int j = 0; j < 4; ++j)
    atomicAdd(&dst[j], a0[j] + a1[j] + a2[j] + a3[j]);
}

extern "C" void kernel_launch(void* const* d_in, const int* in_sizes, int n_in,
                              void* d_out, int out_size, void* d_ws, size_t ws_size,
                              hipStream_t stream) {
  const float* hidden = (const float*)d_in[0];
  const float* enc    = (const float*)d_in[1];
  const int*   mask   = (const int*)d_in[2];
  const float* attn_W = (const float*)d_in[3];
  const float* attn_b = (const float*)d_in[4];
  const float* vW     = (const float*)d_in[5];
  float* out = (float*)d_out;   // [0,65536): context ; [65536,131072): attn_weights

  float* scores = (float*)d_ws;                        // 65536 f32
  float* hb     = scores + 65536;                      // 32768 f32
  unsigned short* weT = (unsigned short*)(hb + 32768); // 524288 bf16 (1 MB)

  hipMemsetAsync(d_ws, 0, (65536 + 32768) * sizeof(float), stream); // scores + hb
  hipMemsetAsync(d_out, 0, 65536 * sizeof(float), stream);          // context region

  hproj_kernel<<<256, 256, 0, stream>>>(hidden, attn_W, hb);
  wet_kernel<<<128, 256, 0, stream>>>(attn_W, weT);
  fused_score_gemm<<<2048, 256, 0, stream>>>(enc, weT, hb, attn_b, vW, scores);
  softmax_kernel<<<64, 256, 0, stream>>>(scores, mask, out + 65536);
  context_kernel<<<1024, 256, 0, stream>>>(out + 65536, enc, out);
}